// Round 19
// baseline (399.549 us; speedup 1.0000x reference)
//
#include <hip/hip_runtime.h>
#include <hip/hip_bf16.h>
#include <math.h>

#define NB 8192
#define NK 4096
#define ND 1024
#define NL 8
#define RES_THR 1e-3f

typedef __bf16 bf16x8 __attribute__((ext_vector_type(8)));
typedef float f32x4 __attribute__((ext_vector_type(4)));
typedef float f32x2 __attribute__((ext_vector_type(2)));

#define MFMA16(a, b, c) __builtin_amdgcn_mfma_f32_16x16x32_bf16(a, b, c, 0, 0, 0)

#define GLOAD(g, l)                                                        \
  __builtin_amdgcn_global_load_lds(                                        \
      (const __attribute__((address_space(1))) void*)(g),                  \
      (__attribute__((address_space(3))) void*)(l), 16, 0, 0)

__device__ __forceinline__ unsigned short f2bf(float x) {
  __hip_bfloat16 h = __float2bfloat16(x);
  return __builtin_bit_cast(unsigned short, h);
}
__device__ __forceinline__ float bf2f(unsigned short u) {
  return __bfloat162float(__builtin_bit_cast(__hip_bfloat16, u));
}

__device__ __forceinline__ float wave_reduce_sum(float v) {
#pragma unroll
  for (int off = 32; off > 0; off >>= 1) v += __shfl_down(v, off);
  return v;
}

// Fused prep+init: b < NK -> Bh row; else -> resid/Ah/active row (b-NK).
__global__ __launch_bounds__(256) void k_setup(const float* __restrict__ cb,
                                               const float* __restrict__ tgt,
                                               unsigned short* __restrict__ Bh,
                                               float* __restrict__ resid,
                                               unsigned short* __restrict__ Ah,
                                               int* __restrict__ active) {
  int b = blockIdx.x, t = threadIdx.x;
  if (b < NK) {
    float4 v = ((const float4*)(cb + (size_t)b * ND))[t];
    ushort4 h;
    h.x = f2bf(v.x); h.y = f2bf(v.y); h.z = f2bf(v.z); h.w = f2bf(v.w);
    ((ushort4*)(Bh + (size_t)b * ND))[t] = h;
    return;
  }
  b -= NK;
  float4 v = ((const float4*)(tgt + (size_t)b * ND))[t];
  ((float4*)(resid + (size_t)b * ND))[t] = v;
  ushort4 h;
  h.x = f2bf(v.x); h.y = f2bf(v.y); h.z = f2bf(v.z); h.w = f2bf(v.w);
  ((ushort4*)(Ah + (size_t)b * ND))[t] = h;
  float ss = v.x * v.x + v.y * v.y + v.z * v.z + v.w * v.w;
  ss = wave_reduce_sum(ss);
  __shared__ float red[4];
  if ((t & 63) == 0) red[t >> 6] = ss;
  __syncthreads();
  if (t == 0) {
    float tot = red[0] + red[1] + red[2] + red[3];
    active[b] = (sqrtf(tot) >= RES_THR) ? 1 : 0;
  }
}

// 256x256-tile bf16 GEMM (8 waves, BK=64, dbuf LDS, counted vmcnt) ->
// bf16 tile of A.B^T. SWZ: bijective XCD-chunk swizzle (chunk = grid/8).
template <int GN, bool SWZ>
__global__ __launch_bounds__(512) void k_gemm(
    const unsigned short* __restrict__ Ah, const unsigned short* __restrict__ Bh,
    unsigned short* __restrict__ sc) {
  __shared__ __align__(16) char sA0[32768];
  __shared__ __align__(16) char sA1[32768];
  __shared__ __align__(16) char sB0[32768];
  __shared__ __align__(16) char sB1[32768];
  const int tid = threadIdx.x;
  const int lane = tid & 63;
  const int cpx = gridDim.x >> 3;  // blocks per XCD chunk
  const int swzid =
      SWZ ? ((blockIdx.x & 7) * cpx + (blockIdx.x >> 3)) : blockIdx.x;
  const int bm = swzid / GN;
  const int bn = swzid % GN;
  const int wid = tid >> 6;
  const int wr = wid >> 2;
  const int wc = wid & 3;

  const int srow = tid >> 3;
  const int sblk = (tid & 7) ^ (srow & 7);
  const unsigned short* aSrc = Ah + (size_t)(bm * 256 + srow) * ND + sblk * 8;
  const unsigned short* bSrc = Bh + (size_t)(bn * 256 + srow) * ND + sblk * 8;

  const int lr = lane & 15;
  const int lk = lane >> 4;
  const int swz = lr & 7;
  const int kb0 = ((lk ^ swz) << 4);
  const int kb1 = (((4 + lk) ^ swz) << 4);

  f32x4 acc[8][4];
#pragma unroll
  for (int m = 0; m < 8; ++m)
#pragma unroll
    for (int n = 0; n < 4; ++n) acc[m][n] = (f32x4)(0.f);

#pragma unroll
  for (int rr = 0; rr < 4; ++rr) {
    GLOAD(aSrc + (size_t)(rr * 64) * ND, sA0 + rr * 8192 + tid * 16);
    GLOAD(bSrc + (size_t)(rr * 64) * ND, sB0 + rr * 8192 + tid * 16);
  }
#pragma unroll
  for (int rr = 0; rr < 4; ++rr) {
    GLOAD(aSrc + (size_t)(rr * 64) * ND + 64, sA1 + rr * 8192 + tid * 16);
    GLOAD(bSrc + (size_t)(rr * 64) * ND + 64, sB1 + rr * 8192 + tid * 16);
  }

#pragma unroll 1
  for (int kt = 0; kt < 16; ++kt) {
    const char* pa = (kt & 1) ? sA1 : sA0;
    const char* pb = (kt & 1) ? sB1 : sB0;
    if (kt < 15) {
      asm volatile("s_waitcnt vmcnt(8)" ::: "memory");
    } else {
      asm volatile("s_waitcnt vmcnt(0)" ::: "memory");
    }
    __builtin_amdgcn_s_barrier();
    bf16x8 af0[8], bf0[4];
#pragma unroll
    for (int m = 0; m < 8; ++m)
      af0[m] = *(const bf16x8*)(pa + (wr * 128 + m * 16 + lr) * 128 + kb0);
#pragma unroll
    for (int n = 0; n < 4; ++n)
      bf0[n] = *(const bf16x8*)(pb + (wc * 64 + n * 16 + lr) * 128 + kb0);
    __builtin_amdgcn_s_setprio(1);
#pragma unroll
    for (int m = 0; m < 8; ++m)
#pragma unroll
      for (int n = 0; n < 4; ++n) acc[m][n] = MFMA16(af0[m], bf0[n], acc[m][n]);
    __builtin_amdgcn_s_setprio(0);
    bf16x8 af1[8], bf1[4];
#pragma unroll
    for (int m = 0; m < 8; ++m)
      af1[m] = *(const bf16x8*)(pa + (wr * 128 + m * 16 + lr) * 128 + kb1);
#pragma unroll
    for (int n = 0; n < 4; ++n)
      bf1[n] = *(const bf16x8*)(pb + (wc * 64 + n * 16 + lr) * 128 + kb1);
    __syncthreads();  // all waves done reading buf[kt&1]
    if (kt < 14) {
      const int k0 = (kt + 2) << 6;
      char* da = (kt & 1) ? sA1 : sA0;
      char* db = (kt & 1) ? sB1 : sB0;
#pragma unroll
      for (int rr = 0; rr < 4; ++rr) {
        GLOAD(aSrc + (size_t)(rr * 64) * ND + k0, da + rr * 8192 + tid * 16);
        GLOAD(bSrc + (size_t)(rr * 64) * ND + k0, db + rr * 8192 + tid * 16);
      }
    }
    __builtin_amdgcn_s_setprio(1);
#pragma unroll
    for (int m = 0; m < 8; ++m)
#pragma unroll
      for (int n = 0; n < 4; ++n) acc[m][n] = MFMA16(af1[m], bf1[n], acc[m][n]);
    __builtin_amdgcn_s_setprio(0);
  }
  __syncthreads();

#pragma unroll
  for (int m = 0; m < 8; ++m) {
    int row = bm * 256 + wr * 128 + m * 16 + lk * 4;
#pragma unroll
    for (int q = 0; q < 4; ++q)
#pragma unroll
      for (int n = 0; n < 4; ++n)
        sc[(size_t)(row + q) * NK + bn * 256 + wc * 64 + n * 16 + lr] =
            f2bf(acc[m][n][q]);
  }
}

// Convert bf16 G -> fp8 e4m3 G (half the gather bytes) + f32 diagonal.
// One block per row; fully coalesced.
__global__ __launch_bounds__(256) void k_convert(
    const unsigned short* __restrict__ Gb, unsigned char* __restrict__ Gf8,
    float* __restrict__ diag) {
  const int row = blockIdx.x, t = threadIdx.x;
  const unsigned short* src = Gb + (size_t)row * NK + t * 16;
  uint4 a = *(const uint4*)(src);
  uint4 b = *(const uint4*)(src + 8);
  unsigned w[8] = {a.x, a.y, a.z, a.w, b.x, b.y, b.z, b.w};
  float f[16];
#pragma unroll
  for (int j = 0; j < 8; ++j) {
    f[2 * j] = bf2f((unsigned short)(w[j] & 0xffff));
    f[2 * j + 1] = bf2f((unsigned short)(w[j] >> 16));
  }
#pragma unroll
  for (int j = 0; j < 16; ++j)
    if (t * 16 + j == row) diag[row] = f[j];
  unsigned o[4];
#pragma unroll
  for (int q = 0; q < 4; ++q) {
    unsigned v = 0;
    v = __builtin_amdgcn_cvt_pk_fp8_f32(f[4 * q + 0], f[4 * q + 1], v, false);
    v = __builtin_amdgcn_cvt_pk_fp8_f32(f[4 * q + 2], f[4 * q + 3], v, true);
    o[q] = v;
  }
  *(uint4*)(Gf8 + (size_t)row * NK + t * 16) =
      make_uint4(o[0], o[1], o[2], o[3]);
}

// Fused full loop, one block per row (R13 proven config). Scores in f32
// registers; fp8 G-row gathers (halved traffic) with exact-f32 diagonal
// substitution; margin 20 for incremental steps; cnt==1 fast path.
__global__ __launch_bounds__(256) void k_all(
    const unsigned short* __restrict__ sc0, const unsigned char* __restrict__ Gf8,
    const float* __restrict__ diag, const float* __restrict__ cb,
    float* __restrict__ resid, float* __restrict__ out_idx,
    const int* __restrict__ active0) {
  const int b = blockIdx.x, t = threadIdx.x;
  __shared__ float s_max[4];
  __shared__ float s_nrm[4];
  __shared__ float s_red[4];
  __shared__ int s_cnt;
  __shared__ int s_spec;
  __shared__ int s_k[64];
  __shared__ float s_bv;
  __shared__ int s_bk;

  float4 r = ((const float4*)(resid + (size_t)b * ND))[t];

  float scv[16];
  {
    const unsigned short* srow = sc0 + (size_t)b * NK;
    uint4 v0 = *(const uint4*)(srow + t * 8);
    uint4 v1 = *(const uint4*)(srow + 2048 + t * 8);
    unsigned w[8] = {v0.x, v0.y, v0.z, v0.w, v1.x, v1.y, v1.z, v1.w};
#pragma unroll
    for (int j = 0; j < 8; ++j) {
      scv[2 * j] = bf2f((unsigned short)(w[j] & 0xffff));
      scv[2 * j + 1] = bf2f((unsigned short)(w[j] >> 16));
    }
  }
  int act = active0[b];
  float decay = 1.0f;

#pragma unroll 1
  for (int s = 0; s < NL; ++s) {
    float m = scv[0];
#pragma unroll
    for (int i = 1; i < 16; ++i) m = fmaxf(m, scv[i]);
    float ss = r.x * r.x + r.y * r.y + r.z * r.z + r.w * r.w;
#pragma unroll
    for (int off = 32; off > 0; off >>= 1) {
      m = fmaxf(m, __shfl_xor(m, off));
      ss += __shfl_xor(ss, off);
    }
    if ((t & 63) == 0) { s_max[t >> 6] = m; s_nrm[t >> 6] = ss; }
    if (t == 0) {
      s_cnt = 0;
      s_spec = 0x7fffffff;
      s_bv = -INFINITY;
      s_bk = 0x7fffffff;
    }
    __syncthreads();
    const float M = fmaxf(fmaxf(s_max[0], s_max[1]), fmaxf(s_max[2], s_max[3]));
    const float nrm = s_nrm[0] + s_nrm[1] + s_nrm[2] + s_nrm[3];
    act = (act && sqrtf(nrm) >= RES_THR) ? 1 : 0;
    const float margin = (s == 0) ? 2.5f : 20.0f;
#pragma unroll
    for (int i = 0; i < 16; ++i) {
      if (scv[i] >= M - margin) {
        int col = (i < 8) ? (t * 8 + i) : (2048 + t * 8 + (i - 8));
        int pos = atomicAdd(&s_cnt, 1);
        if (pos < 64) s_k[pos] = col;
        if (scv[i] == M) atomicMin(&s_spec, col);
      }
    }
    __syncthreads();
    const int cnt = s_cnt < 64 ? s_cnt : 64;
    int kbest;
    if (cnt <= 1) {
      kbest = s_spec;  // sole margin candidate == exact argmax
    } else {
      for (int c = 0; c < cnt; ++c) {
        int k = s_k[c];
        float4 cv = ((const float4*)(cb + (size_t)k * ND))[t];
        float dd = r.x * cv.x + r.y * cv.y + r.z * cv.z + r.w * cv.w;
        dd = wave_reduce_sum(dd);
        if ((t & 63) == 0) s_red[t >> 6] = dd;
        __syncthreads();
        if (t == 0) {
          float scr = s_red[0] + s_red[1] + s_red[2] + s_red[3];
          if (scr > s_bv || (scr == s_bv && k < s_bk)) { s_bv = scr; s_bk = k; }
        }
        __syncthreads();
      }
      kbest = s_bk;
    }
    if (t == 0) out_idx[(size_t)b * NL + s] = act ? (float)kbest : -1.0f;
    if (act) {
      float4 cv = ((const float4*)(cb + (size_t)kbest * ND))[t];
      r.x -= decay * cv.x;
      r.y -= decay * cv.y;
      r.z -= decay * cv.z;
      r.w -= decay * cv.w;
      if (s < NL - 1) {
        const unsigned char* growp = Gf8 + (size_t)kbest * NK;
        uint2 g0 = *(const uint2*)(growp + t * 8);
        uint2 g1 = *(const uint2*)(growp + 2048 + t * 8);
        const float dk = diag[kbest];
        unsigned wv[4] = {g0.x, g0.y, g1.x, g1.y};
#pragma unroll
        for (int q = 0; q < 4; ++q) {
          f32x2 lo = __builtin_amdgcn_cvt_pk_f32_fp8(wv[q], false);
          f32x2 hi = __builtin_amdgcn_cvt_pk_f32_fp8(wv[q], true);
          const int base = (q < 2) ? (t * 8 + q * 4) : (2048 + t * 8 + (q - 2) * 4);
          float v0 = (base + 0 == kbest) ? dk : lo.x;
          float v1 = (base + 1 == kbest) ? dk : lo.y;
          float v2 = (base + 2 == kbest) ? dk : hi.x;
          float v3 = (base + 3 == kbest) ? dk : hi.y;
          scv[q * 4 + 0] -= decay * v0;
          scv[q * 4 + 1] -= decay * v1;
          scv[q * 4 + 2] -= decay * v2;
          scv[q * 4 + 3] -= decay * v3;
        }
      }
    }
    decay *= 0.9f;
    __syncthreads();  // protect s_* resets at top of next step
  }
  ((float4*)(resid + (size_t)b * ND))[t] = r;
}

extern "C" void kernel_launch(void* const* d_in, const int* in_sizes, int n_in,
                              void* d_out, int out_size, void* d_ws,
                              size_t ws_size, hipStream_t stream) {
  const float* targets = (const float*)d_in[0];
  const float* codebook = (const float*)d_in[1];
  float* out = (float*)d_out;
  float* out_idx = out;
  float* resid = out + (size_t)NB * NL;

  char* ws = (char*)d_ws;
  const size_t SC_SZ = (size_t)NB * NK * 2;        // 64MB
  const size_t G_SZ = (size_t)NK * NK * 2;         // 32MB
  const size_t AH_SZ = (size_t)NB * ND * 2;        // 16MB
  const size_t BH_SZ = (size_t)NK * ND * 2;        // 8MB
  const size_t PART_SZ = (size_t)NB * 16 * 16;     // 2MB (diag + slack)

  unsigned short* scores = (unsigned short*)ws;
  unsigned short* G = (unsigned short*)(ws + SC_SZ);
  unsigned short* Ah = (unsigned short*)(ws + SC_SZ + G_SZ);
  unsigned short* Bh = (unsigned short*)(ws + SC_SZ + G_SZ + AH_SZ);
  float* diag = (float*)(ws + SC_SZ + G_SZ + AH_SZ + BH_SZ);  // 16KB in PART
  int* active = (int*)(ws + SC_SZ + G_SZ + AH_SZ + BH_SZ + PART_SZ);
  unsigned char* Gf8 = (unsigned char*)Ah;  // reuse Ah (dead after scores0)

  k_setup<<<NK + NB, 256, 0, stream>>>(codebook, targets, Bh, resid, Ah,
                                       active);
  k_gemm<16, false><<<256, 512, 0, stream>>>(Bh, Bh, G);        // Gram (bf16)
  k_gemm<16, true><<<512, 512, 0, stream>>>(Ah, Bh, scores);    // scores0
  k_convert<<<NK, 256, 0, stream>>>(G, Gf8, diag);              // G -> fp8
  k_all<<<NB, 256, 0, stream>>>(scores, Gf8, diag, codebook, resid, out_idx,
                                active);
}

// Round 20
// 263.029 us; speedup vs baseline: 1.5190x; 1.5190x over previous
//
#include <hip/hip_runtime.h>
#include <hip/hip_bf16.h>
#include <math.h>

#define NB 8192
#define NK 4096
#define ND 1024
#define NL 8
#define RES_THR 1e-3f

typedef __bf16 bf16x8 __attribute__((ext_vector_type(8)));
typedef float f32x4 __attribute__((ext_vector_type(4)));

#define MFMA16(a, b, c) __builtin_amdgcn_mfma_f32_16x16x32_bf16(a, b, c, 0, 0, 0)

#define GLOAD(g, l)                                                        \
  __builtin_amdgcn_global_load_lds(                                        \
      (const __attribute__((address_space(1))) void*)(g),                  \
      (__attribute__((address_space(3))) void*)(l), 16, 0, 0)

__device__ __forceinline__ unsigned short f2bf(float x) {
  __hip_bfloat16 h = __float2bfloat16(x);
  return __builtin_bit_cast(unsigned short, h);
}
__device__ __forceinline__ float bf2f(unsigned short u) {
  return __bfloat162float(__builtin_bit_cast(__hip_bfloat16, u));
}

__device__ __forceinline__ float wave_reduce_sum(float v) {
#pragma unroll
  for (int off = 32; off > 0; off >>= 1) v += __shfl_down(v, off);
  return v;
}

// Fused prep+init: b < NK -> Bh row; else -> resid/Ah/active row (b-NK).
__global__ __launch_bounds__(256) void k_setup(const float* __restrict__ cb,
                                               const float* __restrict__ tgt,
                                               unsigned short* __restrict__ Bh,
                                               float* __restrict__ resid,
                                               unsigned short* __restrict__ Ah,
                                               int* __restrict__ active) {
  int b = blockIdx.x, t = threadIdx.x;
  if (b < NK) {
    float4 v = ((const float4*)(cb + (size_t)b * ND))[t];
    ushort4 h;
    h.x = f2bf(v.x); h.y = f2bf(v.y); h.z = f2bf(v.z); h.w = f2bf(v.w);
    ((ushort4*)(Bh + (size_t)b * ND))[t] = h;
    return;
  }
  b -= NK;
  float4 v = ((const float4*)(tgt + (size_t)b * ND))[t];
  ((float4*)(resid + (size_t)b * ND))[t] = v;
  ushort4 h;
  h.x = f2bf(v.x); h.y = f2bf(v.y); h.z = f2bf(v.z); h.w = f2bf(v.w);
  ((ushort4*)(Ah + (size_t)b * ND))[t] = h;
  float ss = v.x * v.x + v.y * v.y + v.z * v.z + v.w * v.w;
  ss = wave_reduce_sum(ss);
  __shared__ float red[4];
  if ((t & 63) == 0) red[t >> 6] = ss;
  __syncthreads();
  if (t == 0) {
    float tot = red[0] + red[1] + red[2] + red[3];
    active[b] = (sqrtf(tot) >= RES_THR) ? 1 : 0;
  }
}

// 256x256-tile bf16 GEMM (8 waves, BK=64, dbuf LDS, counted vmcnt) ->
// bf16 tile of A.B^T. SWZ: bijective XCD-chunk swizzle (chunk = grid/8).
template <int GN, bool SWZ>
__global__ __launch_bounds__(512) void k_gemm(
    const unsigned short* __restrict__ Ah, const unsigned short* __restrict__ Bh,
    unsigned short* __restrict__ sc) {
  __shared__ __align__(16) char sA0[32768];
  __shared__ __align__(16) char sA1[32768];
  __shared__ __align__(16) char sB0[32768];
  __shared__ __align__(16) char sB1[32768];
  const int tid = threadIdx.x;
  const int lane = tid & 63;
  const int cpx = gridDim.x >> 3;  // blocks per XCD chunk
  const int swzid =
      SWZ ? ((blockIdx.x & 7) * cpx + (blockIdx.x >> 3)) : blockIdx.x;
  const int bm = swzid / GN;
  const int bn = swzid % GN;
  const int wid = tid >> 6;
  const int wr = wid >> 2;
  const int wc = wid & 3;

  const int srow = tid >> 3;
  const int sblk = (tid & 7) ^ (srow & 7);
  const unsigned short* aSrc = Ah + (size_t)(bm * 256 + srow) * ND + sblk * 8;
  const unsigned short* bSrc = Bh + (size_t)(bn * 256 + srow) * ND + sblk * 8;

  const int lr = lane & 15;
  const int lk = lane >> 4;
  const int swz = lr & 7;
  const int kb0 = ((lk ^ swz) << 4);
  const int kb1 = (((4 + lk) ^ swz) << 4);

  f32x4 acc[8][4];
#pragma unroll
  for (int m = 0; m < 8; ++m)
#pragma unroll
    for (int n = 0; n < 4; ++n) acc[m][n] = (f32x4)(0.f);

#pragma unroll
  for (int rr = 0; rr < 4; ++rr) {
    GLOAD(aSrc + (size_t)(rr * 64) * ND, sA0 + rr * 8192 + tid * 16);
    GLOAD(bSrc + (size_t)(rr * 64) * ND, sB0 + rr * 8192 + tid * 16);
  }
#pragma unroll
  for (int rr = 0; rr < 4; ++rr) {
    GLOAD(aSrc + (size_t)(rr * 64) * ND + 64, sA1 + rr * 8192 + tid * 16);
    GLOAD(bSrc + (size_t)(rr * 64) * ND + 64, sB1 + rr * 8192 + tid * 16);
  }

#pragma unroll 1
  for (int kt = 0; kt < 16; ++kt) {
    const char* pa = (kt & 1) ? sA1 : sA0;
    const char* pb = (kt & 1) ? sB1 : sB0;
    if (kt < 15) {
      asm volatile("s_waitcnt vmcnt(8)" ::: "memory");
    } else {
      asm volatile("s_waitcnt vmcnt(0)" ::: "memory");
    }
    __builtin_amdgcn_s_barrier();
    bf16x8 af0[8], bf0[4];
#pragma unroll
    for (int m = 0; m < 8; ++m)
      af0[m] = *(const bf16x8*)(pa + (wr * 128 + m * 16 + lr) * 128 + kb0);
#pragma unroll
    for (int n = 0; n < 4; ++n)
      bf0[n] = *(const bf16x8*)(pb + (wc * 64 + n * 16 + lr) * 128 + kb0);
    __builtin_amdgcn_s_setprio(1);
#pragma unroll
    for (int m = 0; m < 8; ++m)
#pragma unroll
      for (int n = 0; n < 4; ++n) acc[m][n] = MFMA16(af0[m], bf0[n], acc[m][n]);
    __builtin_amdgcn_s_setprio(0);
    bf16x8 af1[8], bf1[4];
#pragma unroll
    for (int m = 0; m < 8; ++m)
      af1[m] = *(const bf16x8*)(pa + (wr * 128 + m * 16 + lr) * 128 + kb1);
#pragma unroll
    for (int n = 0; n < 4; ++n)
      bf1[n] = *(const bf16x8*)(pb + (wc * 64 + n * 16 + lr) * 128 + kb1);
    __syncthreads();  // all waves done reading buf[kt&1]
    if (kt < 14) {
      const int k0 = (kt + 2) << 6;
      char* da = (kt & 1) ? sA1 : sA0;
      char* db = (kt & 1) ? sB1 : sB0;
#pragma unroll
      for (int rr = 0; rr < 4; ++rr) {
        GLOAD(aSrc + (size_t)(rr * 64) * ND + k0, da + rr * 8192 + tid * 16);
        GLOAD(bSrc + (size_t)(rr * 64) * ND + k0, db + rr * 8192 + tid * 16);
      }
    }
    __builtin_amdgcn_s_setprio(1);
#pragma unroll
    for (int m = 0; m < 8; ++m)
#pragma unroll
      for (int n = 0; n < 4; ++n) acc[m][n] = MFMA16(af1[m], bf1[n], acc[m][n]);
    __builtin_amdgcn_s_setprio(0);
  }
  __syncthreads();

#pragma unroll
  for (int m = 0; m < 8; ++m) {
    int row = bm * 256 + wr * 128 + m * 16 + lk * 4;
#pragma unroll
    for (int q = 0; q < 4; ++q)
#pragma unroll
      for (int n = 0; n < 4; ++n)
        sc[(size_t)(row + q) * NK + bn * 256 + wc * 64 + n * 16 + lr] =
            f2bf(acc[m][n][q]);
  }
}

// Fused full loop, one 128-thread block per row (2 waves). Thread owns 32
// score cols (4 segments of 8) + 8 residual dims. bf16 G, margin 6,
// cnt==1 fast path. 2-wave barriers; ~3x resident rows vs 256-thread.
__global__ __launch_bounds__(128) void k_all(
    const unsigned short* __restrict__ sc0, const unsigned short* __restrict__ G,
    const float* __restrict__ cb, float* __restrict__ resid,
    float* __restrict__ out_idx, const int* __restrict__ active0) {
  const int b = blockIdx.x, t = threadIdx.x;  // t in [0,128)
  __shared__ float s_max[2];
  __shared__ float s_nrm[2];
  __shared__ float s_red[2];
  __shared__ int s_cnt;
  __shared__ int s_spec;
  __shared__ int s_k[64];
  __shared__ float s_bv;
  __shared__ int s_bk;

  // residual: thread owns dims [t*8, t*8+8)
  const float4* rbase = (const float4*)(resid + (size_t)b * ND + t * 8);
  float4 r0 = rbase[0], r1 = rbase[1];

  // scores: thread owns cols {seg*1024 + t*8 + j : seg<4, j<8}
  float scv[32];
  {
    const unsigned short* srow = sc0 + (size_t)b * NK;
#pragma unroll
    for (int sg = 0; sg < 4; ++sg) {
      uint4 v = *(const uint4*)(srow + sg * 1024 + t * 8);
      unsigned w[4] = {v.x, v.y, v.z, v.w};
#pragma unroll
      for (int q = 0; q < 4; ++q) {
        scv[sg * 8 + 2 * q] = bf2f((unsigned short)(w[q] & 0xffff));
        scv[sg * 8 + 2 * q + 1] = bf2f((unsigned short)(w[q] >> 16));
      }
    }
  }
  int act = active0[b];
  float decay = 1.0f;

#pragma unroll 1
  for (int s = 0; s < NL; ++s) {
    float m = scv[0];
#pragma unroll
    for (int i = 1; i < 32; ++i) m = fmaxf(m, scv[i]);
    float ss = r0.x * r0.x + r0.y * r0.y + r0.z * r0.z + r0.w * r0.w +
               r1.x * r1.x + r1.y * r1.y + r1.z * r1.z + r1.w * r1.w;
#pragma unroll
    for (int off = 32; off > 0; off >>= 1) {
      m = fmaxf(m, __shfl_xor(m, off));
      ss += __shfl_xor(ss, off);
    }
    if ((t & 63) == 0) { s_max[t >> 6] = m; s_nrm[t >> 6] = ss; }
    if (t == 0) {
      s_cnt = 0;
      s_spec = 0x7fffffff;
      s_bv = -INFINITY;
      s_bk = 0x7fffffff;
    }
    __syncthreads();
    const float M = fmaxf(s_max[0], s_max[1]);
    const float nrm = s_nrm[0] + s_nrm[1];
    act = (act && sqrtf(nrm) >= RES_THR) ? 1 : 0;
    const float margin = (s == 0) ? 2.5f : 6.0f;
#pragma unroll
    for (int i = 0; i < 32; ++i) {
      if (scv[i] >= M - margin) {
        int col = (i >> 3) * 1024 + t * 8 + (i & 7);
        int pos = atomicAdd(&s_cnt, 1);
        if (pos < 64) s_k[pos] = col;
        if (scv[i] == M) atomicMin(&s_spec, col);
      }
    }
    __syncthreads();
    const int cnt = s_cnt < 64 ? s_cnt : 64;
    int kbest;
    if (cnt <= 1) {
      kbest = s_spec;  // sole margin candidate == exact argmax
    } else {
      for (int c = 0; c < cnt; ++c) {
        int k = s_k[c];
        const float4* cbr = (const float4*)(cb + (size_t)k * ND + t * 8);
        float4 c0 = cbr[0], c1 = cbr[1];
        float dd = r0.x * c0.x + r0.y * c0.y + r0.z * c0.z + r0.w * c0.w +
                   r1.x * c1.x + r1.y * c1.y + r1.z * c1.z + r1.w * c1.w;
#pragma unroll
        for (int off = 32; off > 0; off >>= 1) dd += __shfl_xor(dd, off);
        if ((t & 63) == 0) s_red[t >> 6] = dd;
        __syncthreads();
        if (t == 0) {
          float scr = s_red[0] + s_red[1];
          if (scr > s_bv || (scr == s_bv && k < s_bk)) { s_bv = scr; s_bk = k; }
        }
        __syncthreads();
      }
      kbest = s_bk;
    }
    if (t == 0) out_idx[(size_t)b * NL + s] = act ? (float)kbest : -1.0f;
    if (act) {
      const float4* cbr = (const float4*)(cb + (size_t)kbest * ND + t * 8);
      float4 c0 = cbr[0], c1 = cbr[1];
      r0.x -= decay * c0.x; r0.y -= decay * c0.y;
      r0.z -= decay * c0.z; r0.w -= decay * c0.w;
      r1.x -= decay * c1.x; r1.y -= decay * c1.y;
      r1.z -= decay * c1.z; r1.w -= decay * c1.w;
      if (s < NL - 1) {
        const unsigned short* grow = G + (size_t)kbest * NK;
#pragma unroll
        for (int sg = 0; sg < 4; ++sg) {
          uint4 g = *(const uint4*)(grow + sg * 1024 + t * 8);
          unsigned w[4] = {g.x, g.y, g.z, g.w};
#pragma unroll
          for (int q = 0; q < 4; ++q) {
            scv[sg * 8 + 2 * q] -=
                decay * bf2f((unsigned short)(w[q] & 0xffff));
            scv[sg * 8 + 2 * q + 1] -=
                decay * bf2f((unsigned short)(w[q] >> 16));
          }
        }
      }
    }
    decay *= 0.9f;
    __syncthreads();  // protect s_* resets at top of next step
  }
  float4* rw = (float4*)(resid + (size_t)b * ND + t * 8);
  rw[0] = r0;
  rw[1] = r1;
}

extern "C" void kernel_launch(void* const* d_in, const int* in_sizes, int n_in,
                              void* d_out, int out_size, void* d_ws,
                              size_t ws_size, hipStream_t stream) {
  const float* targets = (const float*)d_in[0];
  const float* codebook = (const float*)d_in[1];
  float* out = (float*)d_out;
  float* out_idx = out;
  float* resid = out + (size_t)NB * NL;

  char* ws = (char*)d_ws;
  const size_t SC_SZ = (size_t)NB * NK * 2;        // 64MB
  const size_t G_SZ = (size_t)NK * NK * 2;         // 32MB
  const size_t AH_SZ = (size_t)NB * ND * 2;        // 16MB
  const size_t BH_SZ = (size_t)NK * ND * 2;        // 8MB
  const size_t PART_SZ = (size_t)NB * 16 * 16;     // 2MB (reserved)

  unsigned short* scores = (unsigned short*)ws;
  unsigned short* G = (unsigned short*)(ws + SC_SZ);
  unsigned short* Ah = (unsigned short*)(ws + SC_SZ + G_SZ);
  unsigned short* Bh = (unsigned short*)(ws + SC_SZ + G_SZ + AH_SZ);
  int* active = (int*)(ws + SC_SZ + G_SZ + AH_SZ + BH_SZ + PART_SZ);

  k_setup<<<NK + NB, 256, 0, stream>>>(codebook, targets, Bh, resid, Ah,
                                       active);
  k_gemm<16, false><<<256, 512, 0, stream>>>(Bh, Bh, G);          // Gram
  k_gemm<16, true><<<512, 512, 0, stream>>>(Ah, Bh, scores);      // scores0
  k_all<<<NB, 128, 0, stream>>>(scores, G, codebook, resid, out_idx, active);
}